// Round 13
// baseline (616.256 us; speedup 1.0000x reference)
//
#include <hip/hip_runtime.h>

#define NG 256
#define PI2F 6.28318530717958647692f
// padded LDS complex index: pad 1 float2 per 16 to break bank aliasing
#define PIDX(i) ((i) + ((i) >> 4))

__device__ __forceinline__ float2 f2add(float2 a, float2 b){ return make_float2(a.x+b.x, a.y+b.y); }
__device__ __forceinline__ float2 f2sub(float2 a, float2 b){ return make_float2(a.x-b.x, a.y-b.y); }
__device__ __forceinline__ float2 cmul(float2 a, float2 b){ return make_float2(a.x*b.x - a.y*b.y, a.x*b.y + a.y*b.x); }
__device__ __forceinline__ float comp(float4 v, int p) {
    return p == 0 ? v.x : p == 1 ? v.y : p == 2 ? v.z : v.w;   // only with literal p
}
__device__ __forceinline__ float4 f4fma(float4 a, float4 v, float s) {
    return make_float4(fmaf(v.x, s, a.x), fmaf(v.y, s, a.y),
                       fmaf(v.z, s, a.z), fmaf(v.w, s, a.w));
}
__device__ __forceinline__ float dot4(float4 a, float4 b) {
    return a.x * b.x + a.y * b.y + a.z * b.z + a.w * b.w;
}
// pack two non-negative floats to bf16 pair (round-to-nearest)
__device__ __forceinline__ unsigned int bpack(float lo, float hi) {
    return ((__float_as_uint(lo) + 0x8000u) >> 16)
         | ((__float_as_uint(hi) + 0x8000u) & 0xFFFF0000u);
}

// ---------------------------------------------------------------------------
// 256-pt radix-4 Stockham FFT, 64 threads per FFT unit (u = lane 0..63).
// Buffers a,b PIDX-padded (272 float2). tw[j]=exp(-2πi j/256). Result ends
// back in `a`. ALL threads of the block must call (internal barriers); `act`
// masks work for idle units. (math validated rounds 2-12)
// ---------------------------------------------------------------------------
template<bool INV>
__device__ __forceinline__ void fft256_r4(float2* a, float2* b, const float2* tw,
                                          int u, bool act)
{
#pragma unroll
    for (int st = 0; st < 4; ++st) {
        if (act) {
            const int sl = 2 * st;
            const int q  = u & ((1 << sl) - 1);
            const int j1 = u - q;                 // p << sl  (twiddle index, <64)
            const float2 x0 = a[PIDX(u)];
            const float2 x1 = a[PIDX(u + 64)];
            const float2 x2 = a[PIDX(u + 128)];
            const float2 x3 = a[PIDX(u + 192)];
            float2 w1 = tw[j1];
            if (INV) w1.y = -w1.y;
            const float2 w2 = cmul(w1, w1);
            const float2 w3 = cmul(w1, w2);
            const float2 apc = f2add(x0, x2), amc = f2sub(x0, x2);
            const float2 bpd = f2add(x1, x3), bmd = f2sub(x1, x3);
            const float2 jb  = make_float2(-bmd.y, bmd.x);      // j*(b-d)
            const float2 t0  = f2add(apc, bpd);
            const float2 t2  = f2sub(apc, bpd);
            const float2 t1  = INV ? f2add(amc, jb) : f2sub(amc, jb);
            const float2 t3  = INV ? f2sub(amc, jb) : f2add(amc, jb);
            const int wb = q + (j1 << 2);         // q + 4*s*p
            const int ss = 1 << sl;
            b[PIDX(wb)]          = t0;
            b[PIDX(wb + ss)]     = cmul(w1, t1);
            b[PIDX(wb + 2 * ss)] = cmul(w2, t2);
            b[PIDX(wb + 3 * ss)] = cmul(w3, t3);
        }
        __syncthreads();
        float2* tmp = a; a = b; b = tmp;
    }
}

__device__ __forceinline__ void init_tw(float2* tw, int tid)
{
    if (tid < 256) {
        float s, c;
        __sincosf(-PI2F * (float)tid * (1.f / 256.f), &s, &c);
        tw[tid] = make_float2(c, s);
    }
}

// ---------------------------------------------------------------------------
// R kernel (row pass): 1024 blocks x 256 threads; block = (b, 2 rows y0,y0+1).
// XCD batch affinity: b = blockIdx & 7. (validated rounds 6-12, r12-exact)
// ---------------------------------------------------------------------------
#define R_POOL 19456   // tw 2048 + bufs 8*272*8

__global__ void __launch_bounds__(256)
r_kernel(const float* zin, float* zout,
         const float2* __restrict__ Ct0, const float2* __restrict__ Ct1,
         float2* __restrict__ At, const float* __restrict__ Qb,
         float* __restrict__ outp, int do_d, int do_a)
{
    __shared__ __align__(16) char pool[R_POOL];
    float2* tw   = (float2*)pool;
    float2* bufs = (float2*)(pool + 2048);   // 8 buffers x 272
    const int tid = threadIdx.x;
    const int b   = blockIdx.x & 7;          // XCD affinity
    const int y0  = (blockIdx.x >> 3) * 2;
    const int j   = tid >> 6, u = tid & 63;

    init_tw(tw, tid);

    if (do_d) {
        float2* A = bufs + j * 272;
        float2* B = bufs + (4 + j) * 272;
        const float2* src = ((j & 1) ? Ct1 : Ct0)
                          + ((size_t)(b * NG + y0 + (j >> 1))) * NG;
#pragma unroll
        for (int r4 = 0; r4 < 4; ++r4) {
            const int x = u + 64 * r4;
            A[PIDX(x)] = src[x];
        }
        __syncthreads();
        fft256_r4<true>(A, B, tw, u, true);

        const float sc = 1.f / 256.f;
        float zn01[2];
#pragma unroll
        for (int r = 0; r < 2; ++r) {
            const float2 uvv = (bufs + (2 * r) * 272)[PIDX(tid)];
            const float2 gzz = (bufs + (2 * r + 1) * 272)[PIDX(tid)];
            const float uu = uvv.x * sc, vv = uvv.y * sc;
            const float zx = gzz.x * sc, zy = gzz.y * sc;
            const int idx = (b * NG + y0 + r) * NG + tid;
            const float z0v = zin[idx];
            const float qv  = Qb[idx];
            const float adv = uu * zx + vv * zy;
            const float zn = z0v + 0.01f * (-adv - 0.5f * vv - 0.05f * z0v + qv);
            zout[idx] = zn;
            if (outp) outp[b * (4 * NG * NG) + (y0 + r) * NG + tid] = zn;
            zn01[r] = zn;
        }
        __syncthreads();                      // all bufs reads done
        bufs[PIDX(tid)] = make_float2(zn01[0], zn01[1]);   // pack rows into A0
        __syncthreads();
    } else {
        bufs[PIDX(tid)] = make_float2(zin[(b * NG + y0) * NG + tid],
                                      zin[(b * NG + y0 + 1) * NG + tid]);
        __syncthreads();
    }

    if (do_a) {
        fft256_r4<false>(bufs, bufs + 4 * 272, tw, u, j == 0);
        const int k  = tid;
        const int km = (256 - k) & 255;
        const float2 Zk = bufs[PIDX(k)], Zm = bufs[PIDX(km)];
        const float dx = Zk.x - Zm.x, dy = Zk.y + Zm.y;
        const float4 ov = make_float4(0.5f * (Zk.x + Zm.x), 0.5f * (Zk.y - Zm.y),
                                      0.5f * dy, -0.5f * dx);
        *((float4*)(At + ((size_t)(b * NG + k)) * NG + y0)) = ov;
    }
}

// ---------------------------------------------------------------------------
// COL kernel: 2560 blocks x 512 threads. XCD batch affinity (both role bases
// are multiples of 8). Conv first (dispatch tail = short BC blocks).
//   blocks [0,2048): conv role. ht stored as PACKED BF16 (cell = 32ch x 2B
//     = 64B + 8B pad = 72B): halves conv LDS bytes and instruction count,
//     and shrinks the pool 51.3->36.9 KB (4 blocks/CU instead of 3).
//     Numerically safe: h rel-err ~2^-9 is attenuated x1e-4 before z
//     (Q = Q0 + 0.01*conv2(h); z += 0.01*(...+Q)).
//     conv1: pack 8ch -> one uint4 store per px (rot slot (cgp+hxc+hy)&3).
//     conv2: 256 threads = (4px chunk, quad of 8ch); 18 b128 reads each
//     (half the old 512x18); unpack once per cell; shfl reduce over 4 lanes.
//   blocks [2048,2560): BC role — verbatim validated rounds 6-12.
// conv LDS: zt 2240 | htb 23328 | w1s 1152 | w2s 1152 | b1s 128 | b2s 16
//           => 28016.  BC: tw 2048 + 16x272x8 = 36864.  POOL = 36864.
// NO min-occupancy bound (round 7 lesson: forced VGPR=40 -> 300MB spills).
// ---------------------------------------------------------------------------
#define COL_POOL 36864

__global__ void __launch_bounds__(512)
col_kernel(const float2* __restrict__ At, float2* __restrict__ Ct0,
           float2* __restrict__ Ct1, const float* __restrict__ zsrc,
           const float* __restrict__ Q0, const float* __restrict__ W1,
           const float* __restrict__ b1, const float* __restrict__ W2,
           const float* __restrict__ b2, float* __restrict__ Qb)
{
    __shared__ __align__(16) char pool[COL_POOL];
    const int tid = threadIdx.x;

    if (blockIdx.x < 2048) {
        // ---------------- conv role (bf16 ht) ----------------
        float*  zt  = (float*)pool;                       // 20 x 28 floats
        char*   htb = pool + 2240;                        // 324 cells x 72 B
        float4* w1s = (float4*)(pool + 25568);            // 72 f4
        float4* w2s = (float4*)(pool + 26720);            // 72 f4
        float*  b1s = (float*)(pool + 27872);             // 32 f
        float*  b2s = (float*)(pool + 28000);             // 1 f
        const int cb  = blockIdx.x;
        const int b   = cb & 7;                           // XCD affinity
        const int tile = cb >> 3;                         // 0..255
        const int ty0 = (tile >> 4) * 16, tx0 = (tile & 15) * 16;

        if (tid < 72) {
            w1s[tid] = ((const float4*)W1)[tid];
            w2s[tid] = ((const float4*)W2)[tid];
        }
        if (tid < 32) b1s[tid] = b1[tid];
        if (tid == 0) b2s[0] = b2[0];

        // stage z tile: rows ty0-2..ty0+17, f4 cols tx0-4 .. tx0+19 (6 f4/row)
        for (int i = tid; i < 120; i += 512) {
            const int r = i / 6, c4 = i - r * 6;
            const int gy = ty0 - 2 + r;
            const int gx = tx0 - 4 + 4 * c4;      // f4 fully in- or out-of-image
            float4 v = make_float4(0.f, 0.f, 0.f, 0.f);
            if ((unsigned)gy < 256u && (unsigned)gx < 256u)
                v = *((const float4*)&zsrc[(b * NG + gy) * NG + gx]);
            *((float4*)&zt[r * 28 + 4 * c4]) = v;
        }
        __syncthreads();

        // ---- conv1 + ReLU: thread = (chunk of 4 h-cols, cg-pair); 360 active
        if (tid < 360) {
            const int chunk = tid >> 2, cgp = tid & 3;
            const int hy = chunk / 5, hx0 = (chunk - hy * 5) * 4;
            const int k4 = hx0;                    // zt float col of f4 A
            float4 hacc[8];
#pragma unroll
            for (int c = 0; c < 8; ++c) {
                const float bv = b1s[cgp * 8 + c];
                hacc[c] = make_float4(bv, bv, bv, bv);
            }
#pragma unroll
            for (int dy = 0; dy < 3; ++dy) {
                const float* zrow = &zt[(hy + dy) * 28 + k4];
                const float4 Az = *((const float4*)zrow);
                const float4 Bz = *((const float4*)(zrow + 4));
                const float4 W0 = make_float4(Az.z, Az.w, Bz.x, Bz.y);
                const float4 W1v = make_float4(Az.w, Bz.x, Bz.y, Bz.z);
#pragma unroll
                for (int g = 0; g < 2; ++g) {
                    const float4 wa = w1s[(dy * 3 + 0) * 8 + 2 * cgp + g];
                    const float4 wb = w1s[(dy * 3 + 1) * 8 + 2 * cgp + g];
                    const float4 wc = w1s[(dy * 3 + 2) * 8 + 2 * cgp + g];
                    hacc[4*g+0] = f4fma(f4fma(f4fma(hacc[4*g+0], W0, wa.x), W1v, wb.x), Bz, wc.x);
                    hacc[4*g+1] = f4fma(f4fma(f4fma(hacc[4*g+1], W0, wa.y), W1v, wb.y), Bz, wc.y);
                    hacc[4*g+2] = f4fma(f4fma(f4fma(hacc[4*g+2], W0, wa.z), W1v, wb.z), Bz, wc.z);
                    hacc[4*g+3] = f4fma(f4fma(f4fma(hacc[4*g+3], W0, wa.w), W1v, wb.w), Bz, wc.w);
                }
            }
            const int gyh = ty0 - 1 + hy;
            const bool vy = (unsigned)gyh < 256u;
#pragma unroll
            for (int p = 0; p < 4; ++p) {
                const int hxc = hx0 + p;
                if (hxc < 18) {
                    const float mk = (vy && (unsigned)(tx0 - 1 + hxc) < 256u) ? 1.f : 0.f;
                    float v[8];
#pragma unroll
                    for (int c = 0; c < 8; ++c)
                        v[c] = mk * fmaxf(comp(hacc[c], p), 0.f);
                    uint4 pk;
                    pk.x = bpack(v[0], v[1]);
                    pk.y = bpack(v[2], v[3]);
                    pk.z = bpack(v[4], v[5]);
                    pk.w = bpack(v[6], v[7]);
                    const int rot = (cgp + hxc + hy) & 3;
                    *((uint4*)(htb + (hy * 18 + hxc) * 72 + rot * 16)) = pk;
                }
            }
        }
        __syncthreads();

        // ---- conv2: 256 threads = (chunk of 4 px, quad q of 8 ch)
        if (tid < 256) {
            const int chunk = tid >> 2, q = tid & 3;
            const int oy = chunk >> 2, ox4 = (chunk & 3) * 4;
            float q0 = 0.f, q1 = 0.f, q2 = 0.f, q3 = 0.f;
#pragma unroll
            for (int dy = 0; dy < 3; ++dy) {
                const int rrow = oy + dy;
                const char* hrow = htb + (rrow * 18 + ox4) * 72;
                const float4 wA0 = w2s[(dy * 3 + 0) * 8 + 2 * q];
                const float4 wA1 = w2s[(dy * 3 + 0) * 8 + 2 * q + 1];
                const float4 wB0 = w2s[(dy * 3 + 1) * 8 + 2 * q];
                const float4 wB1 = w2s[(dy * 3 + 1) * 8 + 2 * q + 1];
                const float4 wC0 = w2s[(dy * 3 + 2) * 8 + 2 * q];
                const float4 wC1 = w2s[(dy * 3 + 2) * 8 + 2 * q + 1];
#pragma unroll
                for (int jj = 0; jj < 6; ++jj) {
                    const int rot = (q + ox4 + jj + rrow) & 3;
                    const uint4 hv = *((const uint4*)(hrow + jj * 72 + rot * 16));
                    const float4 lo = make_float4(
                        __uint_as_float(hv.x << 16), __uint_as_float(hv.x & 0xFFFF0000u),
                        __uint_as_float(hv.y << 16), __uint_as_float(hv.y & 0xFFFF0000u));
                    const float4 hi = make_float4(
                        __uint_as_float(hv.z << 16), __uint_as_float(hv.z & 0xFFFF0000u),
                        __uint_as_float(hv.w << 16), __uint_as_float(hv.w & 0xFFFF0000u));
                    if (jj <= 3) {
                        const float d = dot4(lo, wA0) + dot4(hi, wA1);
                        if (jj == 0) q0 += d; else if (jj == 1) q1 += d;
                        else if (jj == 2) q2 += d; else q3 += d;
                    }
                    if (jj >= 1 && jj <= 4) {
                        const float d = dot4(lo, wB0) + dot4(hi, wB1);
                        if (jj == 1) q0 += d; else if (jj == 2) q1 += d;
                        else if (jj == 3) q2 += d; else q3 += d;
                    }
                    if (jj >= 2) {
                        const float d = dot4(lo, wC0) + dot4(hi, wC1);
                        if (jj == 2) q0 += d; else if (jj == 3) q1 += d;
                        else if (jj == 4) q2 += d; else q3 += d;
                    }
                }
            }
#pragma unroll
            for (int s = 1; s < 4; s <<= 1) {
                q0 += __shfl_xor(q0, s); q1 += __shfl_xor(q1, s);
                q2 += __shfl_xor(q2, s); q3 += __shfl_xor(q3, s);
            }
            if (q == 0) {
                const int gy = ty0 + oy, gx = tx0 + ox4;
                const float4 Qv = *((const float4*)&Q0[gy * NG + gx]);
                const float bb = b2s[0];
                const float4 o = make_float4(
                    Qv.x + 0.01f * (q0 + bb), Qv.y + 0.01f * (q1 + bb),
                    Qv.z + 0.01f * (q2 + bb), Qv.w + 0.01f * (q3 + bb));
                *((float4*)&Qb[(b * NG + gy) * NG + gx]) = o;
            }
        }
    } else {
        // ---------------- BC role (8 FFT units) ----------------
        float2* tw   = (float2*)pool;                 // 2048
        float2* bufs = (float2*)(pool + 2048);        // 16 x 272 float2
        const int bid = blockIdx.x - 2048;            // 0..511
        const int b  = bid & 7;                       // XCD affinity
        const int kg = bid >> 3;                      // 0..63
        const int j8 = tid >> 6, u = tid & 63;

        init_tw(tw, tid);
        if (j8 < 4) {
            const int kxl = 4 * kg + j8;
            float2* A = bufs + j8 * 272;
            const float2* src = At + ((size_t)(b * NG + kxl)) * NG;
#pragma unroll
            for (int r = 0; r < 4; ++r) {
                const int x = u + 64 * r;
                A[PIDX(x)] = src[x];
            }
        }
        __syncthreads();
        fft256_r4<false>(bufs + j8 * 272, bufs + (4 + (j8 & 3)) * 272, tw, u, j8 < 4);

        if (tid < 256) {
            const int jl = tid >> 6;                  // line 0..3
            const int kxl = 4 * kg + jl;
            float2* A = bufs + jl * 272;
            float2* C = bufs + (8 + jl) * 272;
            const float kxv = (kxl < 128) ? (float)kxl : (float)(kxl - 256);
            const float kxm = (kxl == 128) ? 0.f : kxv;
#pragma unroll
            for (int r = 0; r < 4; ++r) {
                const int ky = u + 64 * r;
                const float kyv = (ky < 128) ? (float)ky : (float)(ky - 256);
                const float kym = (ky == 128) ? 0.f : kyv;
                const float K2 = kxv * kxv + kyv * kyv;
                const float il = (K2 > 0.f) ? (-1.f / K2) : 0.f;
                const float2 Z = A[PIDX(ky)];
                const float ar = -kxm * il, ai = -kym * il;
                A[PIDX(ky)] = make_float2(ar * Z.x - ai * Z.y, ar * Z.y + ai * Z.x);
                C[PIDX(ky)] = make_float2(-kym * Z.x - kxm * Z.y, -kym * Z.y + kxm * Z.x);
            }
        }
        __syncthreads();

        float2* ia = (j8 < 4) ? bufs + j8 * 272 : bufs + (8 + (j8 - 4)) * 272;
        float2* ib = (j8 < 4) ? bufs + (4 + j8) * 272 : bufs + (12 + (j8 - 4)) * 272;
        fft256_r4<true>(ia, ib, tw, u, true);

        const float sc = 1.f / 256.f;
        const int y = tid & 255;
        float2 ov[4];
        if (tid < 256) {
#pragma unroll
            for (int jj = 0; jj < 4; ++jj) {
                const float2 r0 = (bufs + jj * 272)[PIDX(y)];
                ov[jj] = make_float2(r0.x * sc, r0.y * sc);
            }
            float4* dst = (float4*)(Ct0 + ((size_t)(b * NG + y)) * NG + 4 * kg);
            dst[0] = ((float4*)ov)[0];
            dst[1] = ((float4*)ov)[1];
        } else {
#pragma unroll
            for (int jj = 0; jj < 4; ++jj) {
                const float2 r1 = (bufs + (8 + jj) * 272)[PIDX(y)];
                ov[jj] = make_float2(r1.x * sc, r1.y * sc);
            }
            float4* dst = (float4*)(Ct1 + ((size_t)(b * NG + y)) * NG + 4 * kg);
            dst[0] = ((float4*)ov)[0];
            dst[1] = ((float4*)ov)[1];
        }
    }
}

// ---------------------------------------------------------------------------
extern "C" void kernel_launch(void* const* d_in, const int* in_sizes, int n_in,
                              void* d_out, int out_size, void* d_ws, size_t ws_size,
                              hipStream_t stream)
{
    const float* zeta = (const float*)d_in[0];   // (8,256,256)
    const float* Q0   = (const float*)d_in[1];   // (256,256)
    const float* W1   = (const float*)d_in[2];   // (3,3,1,32)
    const float* b1   = (const float*)d_in[3];   // (32,)
    const float* W2   = (const float*)d_in[4];   // (3,3,32,1)
    const float* b2   = (const float*)d_in[5];   // (1,)
    float* outp = (float*)d_out;                 // (8,4,256,256)

    char* ws = (char*)d_ws;
    float*  zws = (float*)(ws);                        // 2 MB (z, in-place)
    float*  Qb  = (float*)(ws + (2u << 20));           // 2 MB
    float2* At  = (float2*)(ws + (4u << 20));          // 4 MB
    float2* Ct0 = (float2*)(ws + (8u << 20));          // 4 MB
    float2* Ct1 = (float2*)(ws + (12u << 20));         // 4 MB
    if (ws_size < (16u << 20)) return;                 // need 16 MB scratch

    // R0: row-FFT of z0 only
    r_kernel<<<1024, 256, 0, stream>>>(zeta, zws, Ct0, Ct1, At, Qb,
                                       nullptr, 0, 1);
    for (int j = 1; j <= 16; ++j) {
        const float* zp = (j == 1) ? zeta : zws;       // z_{j-1}
        col_kernel<<<2560, 512, 0, stream>>>(At, Ct0, Ct1, zp,
                                             Q0, W1, b1, W2, b2, Qb);
        float* op = (j % 4 == 0) ? (outp + (size_t)(j / 4 - 1) * NG * NG)
                                 : nullptr;
        r_kernel<<<1024, 256, 0, stream>>>(zp, zws, Ct0, Ct1, At, Qb,
                                           op, 1, (j < 16) ? 1 : 0);
    }
}

// Round 14
// 560.253 us; speedup vs baseline: 1.1000x; 1.1000x over previous
//
#include <hip/hip_runtime.h>

#define NG 256
#define PI2F 6.28318530717958647692f
// padded LDS complex index: pad 1 float2 per 16 to break bank aliasing
#define PIDX(i) ((i) + ((i) >> 4))

__device__ __forceinline__ float2 f2add(float2 a, float2 b){ return make_float2(a.x+b.x, a.y+b.y); }
__device__ __forceinline__ float2 f2sub(float2 a, float2 b){ return make_float2(a.x-b.x, a.y-b.y); }
__device__ __forceinline__ float2 cmul(float2 a, float2 b){ return make_float2(a.x*b.x - a.y*b.y, a.x*b.y + a.y*b.x); }
__device__ __forceinline__ float comp(float4 v, int p) {
    return p == 0 ? v.x : p == 1 ? v.y : p == 2 ? v.z : v.w;   // only with literal p
}
__device__ __forceinline__ float4 f4fma(float4 a, float4 v, float s) {
    return make_float4(fmaf(v.x, s, a.x), fmaf(v.y, s, a.y),
                       fmaf(v.z, s, a.z), fmaf(v.w, s, a.w));
}
__device__ __forceinline__ float dot4(float4 a, float4 b) {
    return a.x * b.x + a.y * b.y + a.z * b.z + a.w * b.w;
}

// ---------------------------------------------------------------------------
// 256-pt radix-4 Stockham FFT, 64 threads per FFT unit (u = lane 0..63).
// Buffers a,b PIDX-padded (272 float2). tw[j]=exp(-2πi j/256). Result ends
// back in `a`. ALL threads of the block must call (internal barriers); `act`
// masks work for idle units. (math validated rounds 2-13)
// ---------------------------------------------------------------------------
template<bool INV>
__device__ __forceinline__ void fft256_r4(float2* a, float2* b, const float2* tw,
                                          int u, bool act)
{
#pragma unroll
    for (int st = 0; st < 4; ++st) {
        if (act) {
            const int sl = 2 * st;
            const int q  = u & ((1 << sl) - 1);
            const int j1 = u - q;                 // p << sl  (twiddle index, <64)
            const float2 x0 = a[PIDX(u)];
            const float2 x1 = a[PIDX(u + 64)];
            const float2 x2 = a[PIDX(u + 128)];
            const float2 x3 = a[PIDX(u + 192)];
            float2 w1 = tw[j1];
            if (INV) w1.y = -w1.y;
            const float2 w2 = cmul(w1, w1);
            const float2 w3 = cmul(w1, w2);
            const float2 apc = f2add(x0, x2), amc = f2sub(x0, x2);
            const float2 bpd = f2add(x1, x3), bmd = f2sub(x1, x3);
            const float2 jb  = make_float2(-bmd.y, bmd.x);      // j*(b-d)
            const float2 t0  = f2add(apc, bpd);
            const float2 t2  = f2sub(apc, bpd);
            const float2 t1  = INV ? f2add(amc, jb) : f2sub(amc, jb);
            const float2 t3  = INV ? f2sub(amc, jb) : f2add(amc, jb);
            const int wb = q + (j1 << 2);         // q + 4*s*p
            const int ss = 1 << sl;
            b[PIDX(wb)]          = t0;
            b[PIDX(wb + ss)]     = cmul(w1, t1);
            b[PIDX(wb + 2 * ss)] = cmul(w2, t2);
            b[PIDX(wb + 3 * ss)] = cmul(w3, t3);
        }
        __syncthreads();
        float2* tmp = a; a = b; b = tmp;
    }
}

__device__ __forceinline__ void init_tw(float2* tw, int tid)
{
    if (tid < 256) {
        float s, c;
        __sincosf(-PI2F * (float)tid * (1.f / 256.f), &s, &c);
        tw[tid] = make_float2(c, s);
    }
}

// ---------------------------------------------------------------------------
// R kernel (row pass): 512 blocks x 512 threads; block = (b, 4 rows y0..y0+3).
// XCD batch affinity: b = blockIdx & 7. (r11 R, isolated A/B this round:
// halves barrier-stages per row — D = 8 units one round, A = 2 packed units.)
//   do_d: D = inverse row-FFT of Ct (8 units: 4 rows x 2 fields, ALL threads
//         active) + pointwise update (z in-place OK: same-thread r/w only)
//   do_a: A = 2 packed fwd row-FFTs (rows 2rp,2rp+1) + Hermitian unpack
//         -> At[b][kx][y0..y0+3] (16B lane writes per half)
// ---------------------------------------------------------------------------
#define R_POOL 36864   // tw 2048 + 16 bufs x 272 x 8B

__global__ void __launch_bounds__(512)
r_kernel(const float* zin, float* zout,
         const float2* __restrict__ Ct0, const float2* __restrict__ Ct1,
         float2* __restrict__ At, const float* __restrict__ Qb,
         float* __restrict__ outp, int do_d, int do_a)
{
    __shared__ __align__(16) char pool[R_POOL];
    float2* tw   = (float2*)pool;
    float2* bufs = (float2*)(pool + 2048);   // 16 buffers x 272
    const int tid = threadIdx.x;
    const int b   = blockIdx.x & 7;          // XCD affinity
    const int y0  = (blockIdx.x >> 3) * 4;
    const int j   = tid >> 6, u = tid & 63;  // j in [0,8)
    const int col = tid & 255, rp = tid >> 8; // update/pack coords

    init_tw(tw, tid);

    if (do_d) {
        // ---- D: unit j -> (row y0 + (j>>1), field j&1)
        float2* A = bufs + j * 272;
        float2* B = bufs + (8 + j) * 272;
        const float2* src = ((j & 1) ? Ct1 : Ct0)
                          + ((size_t)(b * NG + y0 + (j >> 1))) * NG;
#pragma unroll
        for (int r4 = 0; r4 < 4; ++r4) {
            const int x = u + 64 * r4;
            A[PIDX(x)] = src[x];
        }
        __syncthreads();
        fft256_r4<true>(A, B, tw, u, true);   // 8 units, all threads active

        // ---- update: thread (rp,col) handles rows 2rp, 2rp+1 at column col
        const float sc = 1.f / 256.f;
        float zn01[2];
#pragma unroll
        for (int r = 0; r < 2; ++r) {
            const int rr = 2 * rp + r;        // row 0..3
            const float2 uvv = (bufs + (2 * rr) * 272)[PIDX(col)];
            const float2 gzz = (bufs + (2 * rr + 1) * 272)[PIDX(col)];
            const float uu = uvv.x * sc, vv = uvv.y * sc;
            const float zx = gzz.x * sc, zy = gzz.y * sc;
            const int idx = (b * NG + y0 + rr) * NG + col;
            const float z0v = zin[idx];
            const float qv  = Qb[idx];
            const float adv = uu * zx + vv * zy;
            const float zn = z0v + 0.01f * (-adv - 0.5f * vv - 0.05f * z0v + qv);
            zout[idx] = zn;
            if (outp) outp[b * (4 * NG * NG) + (y0 + rr) * NG + col] = zn;
            zn01[r] = zn;
        }
        __syncthreads();                      // all bufs reads done
        // pack rows (2rp, 2rp+1) into buffer 2*rp
        (bufs + 2 * rp * 272)[PIDX(col)] = make_float2(zn01[0], zn01[1]);
        __syncthreads();
    } else {
        // first dispatch: pack z0 rows directly from global
        (bufs + 2 * rp * 272)[PIDX(col)] =
            make_float2(zin[(b * NG + y0 + 2 * rp) * NG + col],
                        zin[(b * NG + y0 + 2 * rp + 1) * NG + col]);
        __syncthreads();
    }

    if (do_a) {
        // ---- A: 2 packed fwd FFTs; unit jj (0,1) on buffer 2*jj
        const int jj = (j < 2) ? j : 1;       // clamp for inactive units
        fft256_r4<false>(bufs + 2 * jj * 272, bufs + (8 + 2 * jj) * 272,
                         tw, u, j < 2);
        // Hermitian unpack; thread (rp,col): k=col, rows y0+2rp..y0+2rp+1
        const int k  = col;
        const int km = (256 - k) & 255;
        const float2* Aj = bufs + 2 * rp * 272;
        const float2 Zk = Aj[PIDX(k)], Zm = Aj[PIDX(km)];
        const float dx = Zk.x - Zm.x, dy = Zk.y + Zm.y;
        const float4 ov = make_float4(0.5f * (Zk.x + Zm.x), 0.5f * (Zk.y - Zm.y),
                                      0.5f * dy, -0.5f * dx);
        *((float4*)(At + ((size_t)(b * NG + k)) * NG + y0 + 2 * rp)) = ov;
    }
}

// ---------------------------------------------------------------------------
// COL kernel: 2560 blocks x 512 threads. XCD batch affinity (both role bases
// are multiples of 8). r12-verbatim (best measured).
//   blocks [0,2048): conv role — f4-vectorized, 16x16 tile, parity-fixed
//     ht slot rotation ((..+hy)&7). Conv first: dispatch tail = short BC.
//   blocks [2048,2560): BC role — fwd FFT along y (4 kx-lines), spectral
//     multiplies (Hermitian-projection Nyquist masks), BOTH packed inverse
//     FFTs in one round (8 units), coalesced writes Ct[f][b][y][kx] x 1/256.
// NO min-occupancy bound (round 7 lesson: forced VGPR=40 -> 300MB spills).
// ---------------------------------------------------------------------------
#define COL_POOL 51344

__global__ void __launch_bounds__(512)
col_kernel(const float2* __restrict__ At, float2* __restrict__ Ct0,
           float2* __restrict__ Ct1, const float* __restrict__ zsrc,
           const float* __restrict__ Q0, const float* __restrict__ W1,
           const float* __restrict__ b1, const float* __restrict__ W2,
           const float* __restrict__ b2, float* __restrict__ Qb)
{
    __shared__ __align__(16) char pool[COL_POOL];
    const int tid = threadIdx.x;

    if (blockIdx.x < 2048) {
        // ---------------- conv role ----------------
        float*  zt  = (float*)pool;                       // 20 x 28 floats
        float*  ht  = (float*)(pool + 2240);              // 324 cells x 36 f
        float4* w1s = (float4*)(pool + 48896);            // 72 f4
        float4* w2s = (float4*)(pool + 50048);            // 72 f4
        float*  b1s = (float*)(pool + 51200);             // 32 f
        float*  b2s = (float*)(pool + 51328);             // 1 f
        const int cb  = blockIdx.x;
        const int b   = cb & 7;                           // XCD affinity
        const int tile = cb >> 3;                         // 0..255
        const int ty0 = (tile >> 4) * 16, tx0 = (tile & 15) * 16;

        if (tid < 72) {
            w1s[tid] = ((const float4*)W1)[tid];
            w2s[tid] = ((const float4*)W2)[tid];
        }
        if (tid < 32) b1s[tid] = b1[tid];
        if (tid == 0) b2s[0] = b2[0];

        // stage z tile: rows ty0-2..ty0+17, f4 cols tx0-4 .. tx0+19 (6 f4/row)
        for (int i = tid; i < 120; i += 512) {
            const int r = i / 6, c4 = i - r * 6;
            const int gy = ty0 - 2 + r;
            const int gx = tx0 - 4 + 4 * c4;      // f4 fully in- or out-of-image
            float4 v = make_float4(0.f, 0.f, 0.f, 0.f);
            if ((unsigned)gy < 256u && (unsigned)gx < 256u)
                v = *((const float4*)&zsrc[(b * NG + gy) * NG + gx]);
            *((float4*)&zt[r * 28 + 4 * c4]) = v;
        }
        __syncthreads();

        // ---- conv1 + ReLU: thread = (chunk of 4 h-cols, cg-pair); 360 active
        if (tid < 360) {
            const int chunk = tid >> 2, cgp = tid & 3;
            const int hy = chunk / 5, hx0 = (chunk - hy * 5) * 4;
            const int k4 = hx0;                    // zt float col of f4 A
            float4 hacc[8];
#pragma unroll
            for (int c = 0; c < 8; ++c) {
                const float bv = b1s[cgp * 8 + c];
                hacc[c] = make_float4(bv, bv, bv, bv);
            }
#pragma unroll
            for (int dy = 0; dy < 3; ++dy) {
                const float* zrow = &zt[(hy + dy) * 28 + k4];
                const float4 Az = *((const float4*)zrow);
                const float4 Bz = *((const float4*)(zrow + 4));
                const float4 W0 = make_float4(Az.z, Az.w, Bz.x, Bz.y);
                const float4 W1v = make_float4(Az.w, Bz.x, Bz.y, Bz.z);
#pragma unroll
                for (int g = 0; g < 2; ++g) {
                    const float4 wa = w1s[(dy * 3 + 0) * 8 + 2 * cgp + g];
                    const float4 wb = w1s[(dy * 3 + 1) * 8 + 2 * cgp + g];
                    const float4 wc = w1s[(dy * 3 + 2) * 8 + 2 * cgp + g];
                    hacc[4*g+0] = f4fma(f4fma(f4fma(hacc[4*g+0], W0, wa.x), W1v, wb.x), Bz, wc.x);
                    hacc[4*g+1] = f4fma(f4fma(f4fma(hacc[4*g+1], W0, wa.y), W1v, wb.y), Bz, wc.y);
                    hacc[4*g+2] = f4fma(f4fma(f4fma(hacc[4*g+2], W0, wa.z), W1v, wb.z), Bz, wc.z);
                    hacc[4*g+3] = f4fma(f4fma(f4fma(hacc[4*g+3], W0, wa.w), W1v, wb.w), Bz, wc.w);
                }
            }
            const int gyh = ty0 - 1 + hy;
            const bool vy = (unsigned)gyh < 256u;
#pragma unroll
            for (int p = 0; p < 4; ++p) {
                const int hxc = hx0 + p;
                if (hxc < 18) {
                    const float mk = (vy && (unsigned)(tx0 - 1 + hxc) < 256u) ? 1.f : 0.f;
                    float* cellp = &ht[(hy * 18 + hxc) * 36];
                    const int s0 = ((2 * cgp + 0 + hxc + hy) & 7) << 2;
                    const int s1 = ((2 * cgp + 1 + hxc + hy) & 7) << 2;
                    const float4 lo = make_float4(
                        mk * fmaxf(comp(hacc[0], p), 0.f), mk * fmaxf(comp(hacc[1], p), 0.f),
                        mk * fmaxf(comp(hacc[2], p), 0.f), mk * fmaxf(comp(hacc[3], p), 0.f));
                    const float4 hi = make_float4(
                        mk * fmaxf(comp(hacc[4], p), 0.f), mk * fmaxf(comp(hacc[5], p), 0.f),
                        mk * fmaxf(comp(hacc[6], p), 0.f), mk * fmaxf(comp(hacc[7], p), 0.f));
                    *((float4*)(cellp + s0)) = lo;
                    *((float4*)(cellp + s1)) = hi;
                }
            }
        }
        __syncthreads();

        // ---- conv2: thread = (chunk of 4 output px, cg); shfl reduce over cg
        {
            const int chunk = tid >> 3, cg = tid & 7;
            const int oy = chunk >> 2, ox4 = (chunk & 3) * 4;
            float q0 = 0.f, q1 = 0.f, q2 = 0.f, q3 = 0.f;
#pragma unroll
            for (int dy = 0; dy < 3; ++dy) {
                const float* hrow = &ht[((oy + dy) * 18 + ox4) * 36];
                const float4 wA = w2s[(dy * 3 + 0) * 8 + cg];
                const float4 wB = w2s[(dy * 3 + 1) * 8 + cg];
                const float4 wC = w2s[(dy * 3 + 2) * 8 + cg];
#pragma unroll
                for (int jj = 0; jj < 6; ++jj) {
                    const float4 hv = *((const float4*)(hrow + jj * 36
                                        + (((cg + ox4 + jj + oy + dy) & 7) << 2)));
                    if (jj <= 3) {
                        const float d = dot4(hv, wA);
                        if (jj == 0) q0 += d; else if (jj == 1) q1 += d;
                        else if (jj == 2) q2 += d; else q3 += d;
                    }
                    if (jj >= 1 && jj <= 4) {
                        const float d = dot4(hv, wB);
                        if (jj == 1) q0 += d; else if (jj == 2) q1 += d;
                        else if (jj == 3) q2 += d; else q3 += d;
                    }
                    if (jj >= 2) {
                        const float d = dot4(hv, wC);
                        if (jj == 2) q0 += d; else if (jj == 3) q1 += d;
                        else if (jj == 4) q2 += d; else q3 += d;
                    }
                }
            }
#pragma unroll
            for (int s = 1; s < 8; s <<= 1) {
                q0 += __shfl_xor(q0, s); q1 += __shfl_xor(q1, s);
                q2 += __shfl_xor(q2, s); q3 += __shfl_xor(q3, s);
            }
            if (cg == 0) {
                const int gy = ty0 + oy, gx = tx0 + ox4;
                const float4 Qv = *((const float4*)&Q0[gy * NG + gx]);
                const float bb = b2s[0];
                const float4 o = make_float4(
                    Qv.x + 0.01f * (q0 + bb), Qv.y + 0.01f * (q1 + bb),
                    Qv.z + 0.01f * (q2 + bb), Qv.w + 0.01f * (q3 + bb));
                *((float4*)&Qb[(b * NG + gy) * NG + gx]) = o;
            }
        }
    } else {
        // ---------------- BC role (8 FFT units) ----------------
        float2* tw   = (float2*)pool;                 // 2048
        float2* bufs = (float2*)(pool + 2048);        // 16 x 272 float2
        const int bid = blockIdx.x - 2048;            // 0..511
        const int b  = bid & 7;                       // XCD affinity
        const int kg = bid >> 3;                      // 0..63
        const int j8 = tid >> 6, u = tid & 63;

        init_tw(tw, tid);
        if (j8 < 4) {
            const int kxl = 4 * kg + j8;
            float2* A = bufs + j8 * 272;
            const float2* src = At + ((size_t)(b * NG + kxl)) * NG;
#pragma unroll
            for (int r = 0; r < 4; ++r) {
                const int x = u + 64 * r;
                A[PIDX(x)] = src[x];
            }
        }
        __syncthreads();
        fft256_r4<false>(bufs + j8 * 272, bufs + (4 + (j8 & 3)) * 272, tw, u, j8 < 4);

        if (tid < 256) {
            const int jl = tid >> 6;                  // line 0..3
            const int kxl = 4 * kg + jl;
            float2* A = bufs + jl * 272;
            float2* C = bufs + (8 + jl) * 272;
            const float kxv = (kxl < 128) ? (float)kxl : (float)(kxl - 256);
            const float kxm = (kxl == 128) ? 0.f : kxv;
#pragma unroll
            for (int r = 0; r < 4; ++r) {
                const int ky = u + 64 * r;
                const float kyv = (ky < 128) ? (float)ky : (float)(ky - 256);
                const float kym = (ky == 128) ? 0.f : kyv;
                const float K2 = kxv * kxv + kyv * kyv;
                const float il = (K2 > 0.f) ? (-1.f / K2) : 0.f;
                const float2 Z = A[PIDX(ky)];
                const float ar = -kxm * il, ai = -kym * il;
                A[PIDX(ky)] = make_float2(ar * Z.x - ai * Z.y, ar * Z.y + ai * Z.x);
                C[PIDX(ky)] = make_float2(-kym * Z.x - kxm * Z.y, -kym * Z.y + kxm * Z.x);
            }
        }
        __syncthreads();

        float2* ia = (j8 < 4) ? bufs + j8 * 272 : bufs + (8 + (j8 - 4)) * 272;
        float2* ib = (j8 < 4) ? bufs + (4 + j8) * 272 : bufs + (12 + (j8 - 4)) * 272;
        fft256_r4<true>(ia, ib, tw, u, true);

        const float sc = 1.f / 256.f;
        const int y = tid & 255;
        float2 ov[4];
        if (tid < 256) {
#pragma unroll
            for (int jj = 0; jj < 4; ++jj) {
                const float2 r0 = (bufs + jj * 272)[PIDX(y)];
                ov[jj] = make_float2(r0.x * sc, r0.y * sc);
            }
            float4* dst = (float4*)(Ct0 + ((size_t)(b * NG + y)) * NG + 4 * kg);
            dst[0] = ((float4*)ov)[0];
            dst[1] = ((float4*)ov)[1];
        } else {
#pragma unroll
            for (int jj = 0; jj < 4; ++jj) {
                const float2 r1 = (bufs + (8 + jj) * 272)[PIDX(y)];
                ov[jj] = make_float2(r1.x * sc, r1.y * sc);
            }
            float4* dst = (float4*)(Ct1 + ((size_t)(b * NG + y)) * NG + 4 * kg);
            dst[0] = ((float4*)ov)[0];
            dst[1] = ((float4*)ov)[1];
        }
    }
}

// ---------------------------------------------------------------------------
extern "C" void kernel_launch(void* const* d_in, const int* in_sizes, int n_in,
                              void* d_out, int out_size, void* d_ws, size_t ws_size,
                              hipStream_t stream)
{
    const float* zeta = (const float*)d_in[0];   // (8,256,256)
    const float* Q0   = (const float*)d_in[1];   // (256,256)
    const float* W1   = (const float*)d_in[2];   // (3,3,1,32)
    const float* b1   = (const float*)d_in[3];   // (32,)
    const float* W2   = (const float*)d_in[4];   // (3,3,32,1)
    const float* b2   = (const float*)d_in[5];   // (1,)
    float* outp = (float*)d_out;                 // (8,4,256,256)

    char* ws = (char*)d_ws;
    float*  zws = (float*)(ws);                        // 2 MB (z, in-place)
    float*  Qb  = (float*)(ws + (2u << 20));           // 2 MB
    float2* At  = (float2*)(ws + (4u << 20));          // 4 MB
    float2* Ct0 = (float2*)(ws + (8u << 20));          // 4 MB
    float2* Ct1 = (float2*)(ws + (12u << 20));         // 4 MB
    if (ws_size < (16u << 20)) return;                 // need 16 MB scratch

    // R0: row-FFT of z0 only
    r_kernel<<<512, 512, 0, stream>>>(zeta, zws, Ct0, Ct1, At, Qb,
                                      nullptr, 0, 1);
    for (int j = 1; j <= 16; ++j) {
        const float* zp = (j == 1) ? zeta : zws;       // z_{j-1}
        col_kernel<<<2560, 512, 0, stream>>>(At, Ct0, Ct1, zp,
                                             Q0, W1, b1, W2, b2, Qb);
        float* op = (j % 4 == 0) ? (outp + (size_t)(j / 4 - 1) * NG * NG)
                                 : nullptr;
        r_kernel<<<512, 512, 0, stream>>>(zp, zws, Ct0, Ct1, At, Qb,
                                          op, 1, (j < 16) ? 1 : 0);
    }
}

// Round 15
// 539.361 us; speedup vs baseline: 1.1426x; 1.0387x over previous
//
#include <hip/hip_runtime.h>

#define NG 256
#define PI2F 6.28318530717958647692f
// padded LDS complex index: pad 1 float2 per 16 to break bank aliasing
#define PIDX(i) ((i) + ((i) >> 4))

__device__ __forceinline__ float2 f2add(float2 a, float2 b){ return make_float2(a.x+b.x, a.y+b.y); }
__device__ __forceinline__ float2 f2sub(float2 a, float2 b){ return make_float2(a.x-b.x, a.y-b.y); }
__device__ __forceinline__ float2 cmul(float2 a, float2 b){ return make_float2(a.x*b.x - a.y*b.y, a.x*b.y + a.y*b.x); }
__device__ __forceinline__ float comp(float4 v, int p) {
    return p == 0 ? v.x : p == 1 ? v.y : p == 2 ? v.z : v.w;   // only with literal p
}
__device__ __forceinline__ float4 f4fma(float4 a, float4 v, float s) {
    return make_float4(fmaf(v.x, s, a.x), fmaf(v.y, s, a.y),
                       fmaf(v.z, s, a.z), fmaf(v.w, s, a.w));
}
__device__ __forceinline__ float dot4(float4 a, float4 b) {
    return a.x * b.x + a.y * b.y + a.z * b.z + a.w * b.w;
}

// ---------------------------------------------------------------------------
// 256-pt radix-4 Stockham FFT, 64 threads per FFT unit (u = lane 0..63).
// Buffers a,b PIDX-padded (272 float2). tw[j]=exp(-2πi j/256). Result ends
// back in `a`. ALL threads of the block must call (internal barriers); `act`
// masks work for idle units. (math validated rounds 2-14)
// ---------------------------------------------------------------------------
template<bool INV>
__device__ __forceinline__ void fft256_r4(float2* a, float2* b, const float2* tw,
                                          int u, bool act)
{
#pragma unroll
    for (int st = 0; st < 4; ++st) {
        if (act) {
            const int sl = 2 * st;
            const int q  = u & ((1 << sl) - 1);
            const int j1 = u - q;                 // p << sl  (twiddle index, <64)
            const float2 x0 = a[PIDX(u)];
            const float2 x1 = a[PIDX(u + 64)];
            const float2 x2 = a[PIDX(u + 128)];
            const float2 x3 = a[PIDX(u + 192)];
            float2 w1 = tw[j1];
            if (INV) w1.y = -w1.y;
            const float2 w2 = cmul(w1, w1);
            const float2 w3 = cmul(w1, w2);
            const float2 apc = f2add(x0, x2), amc = f2sub(x0, x2);
            const float2 bpd = f2add(x1, x3), bmd = f2sub(x1, x3);
            const float2 jb  = make_float2(-bmd.y, bmd.x);      // j*(b-d)
            const float2 t0  = f2add(apc, bpd);
            const float2 t2  = f2sub(apc, bpd);
            const float2 t1  = INV ? f2add(amc, jb) : f2sub(amc, jb);
            const float2 t3  = INV ? f2sub(amc, jb) : f2add(amc, jb);
            const int wb = q + (j1 << 2);         // q + 4*s*p
            const int ss = 1 << sl;
            b[PIDX(wb)]          = t0;
            b[PIDX(wb + ss)]     = cmul(w1, t1);
            b[PIDX(wb + 2 * ss)] = cmul(w2, t2);
            b[PIDX(wb + 3 * ss)] = cmul(w3, t3);
        }
        __syncthreads();
        float2* tmp = a; a = b; b = tmp;
    }
}

__device__ __forceinline__ void init_tw(float2* tw, int tid)
{
    if (tid < 256) {
        float s, c;
        __sincosf(-PI2F * (float)tid * (1.f / 256.f), &s, &c);
        tw[tid] = make_float2(c, s);
    }
}

// ---------------------------------------------------------------------------
// R kernel (row pass): 1024 blocks x 256 threads; block = (b, 2 rows y0,y0+1).
// XCD batch affinity: b = blockIdx & 7. (r12-exact + early zin/Qb prefetch:
// update operands issued at entry so 8 FFT barrier-stages hide L2 latency.)
//   do_d: D = inverse row-FFT of Ct (4 units: 2 rows x 2 fields) + pointwise
//         update (z in-place OK: same-thread read/write only)
//   do_a: A = packed fwd row-FFT of the two fresh rows + Hermitian unpack
//         -> At[b][kx][y0..y0+1] (16B lane writes)
// ---------------------------------------------------------------------------
#define R_POOL 19456   // tw 2048 + bufs 8*272*8

__global__ void __launch_bounds__(256)
r_kernel(const float* zin, float* zout,
         const float2* __restrict__ Ct0, const float2* __restrict__ Ct1,
         float2* __restrict__ At, const float* __restrict__ Qb,
         float* __restrict__ outp, int do_d, int do_a)
{
    __shared__ __align__(16) char pool[R_POOL];
    float2* tw   = (float2*)pool;
    float2* bufs = (float2*)(pool + 2048);   // 8 buffers x 272
    const int tid = threadIdx.x;
    const int b   = blockIdx.x & 7;          // XCD affinity
    const int y0  = (blockIdx.x >> 3) * 2;
    const int j   = tid >> 6, u = tid & 63;

    init_tw(tw, tid);

    if (do_d) {
        // ---- prefetch update operands (hidden under FFT barrier-stages)
        float z0pre[2], qpre[2];
#pragma unroll
        for (int r = 0; r < 2; ++r) {
            const int idx = (b * NG + y0 + r) * NG + tid;
            z0pre[r] = zin[idx];              // safe in-place: own element only
            qpre[r]  = Qb[idx];
        }

        float2* A = bufs + j * 272;
        float2* B = bufs + (4 + j) * 272;
        const float2* src = ((j & 1) ? Ct1 : Ct0)
                          + ((size_t)(b * NG + y0 + (j >> 1))) * NG;
#pragma unroll
        for (int r4 = 0; r4 < 4; ++r4) {
            const int x = u + 64 * r4;
            A[PIDX(x)] = src[x];
        }
        __syncthreads();
        fft256_r4<true>(A, B, tw, u, true);

        const float sc = 1.f / 256.f;
        float zn01[2];
#pragma unroll
        for (int r = 0; r < 2; ++r) {
            const float2 uvv = (bufs + (2 * r) * 272)[PIDX(tid)];
            const float2 gzz = (bufs + (2 * r + 1) * 272)[PIDX(tid)];
            const float uu = uvv.x * sc, vv = uvv.y * sc;
            const float zx = gzz.x * sc, zy = gzz.y * sc;
            const int idx = (b * NG + y0 + r) * NG + tid;
            const float adv = uu * zx + vv * zy;
            const float zn = z0pre[r]
                + 0.01f * (-adv - 0.5f * vv - 0.05f * z0pre[r] + qpre[r]);
            zout[idx] = zn;
            if (outp) outp[b * (4 * NG * NG) + (y0 + r) * NG + tid] = zn;
            zn01[r] = zn;
        }
        __syncthreads();                      // all bufs reads done
        bufs[PIDX(tid)] = make_float2(zn01[0], zn01[1]);   // pack rows into A0
        __syncthreads();
    } else {
        bufs[PIDX(tid)] = make_float2(zin[(b * NG + y0) * NG + tid],
                                      zin[(b * NG + y0 + 1) * NG + tid]);
        __syncthreads();
    }

    if (do_a) {
        fft256_r4<false>(bufs, bufs + 4 * 272, tw, u, j == 0);
        const int k  = tid;
        const int km = (256 - k) & 255;
        const float2 Zk = bufs[PIDX(k)], Zm = bufs[PIDX(km)];
        const float dx = Zk.x - Zm.x, dy = Zk.y + Zm.y;
        const float4 ov = make_float4(0.5f * (Zk.x + Zm.x), 0.5f * (Zk.y - Zm.y),
                                      0.5f * dy, -0.5f * dx);
        *((float4*)(At + ((size_t)(b * NG + k)) * NG + y0)) = ov;
    }
}

// ---------------------------------------------------------------------------
// COL kernel: 2560 blocks x 512 threads. XCD batch affinity (both role bases
// are multiples of 8). r12-verbatim + early Q0 prefetch in conv role.
//   blocks [0,2048): conv role — f4-vectorized, 16x16 tile, parity-fixed
//     ht slot rotation ((..+hy)&7). Conv first: dispatch tail = short BC.
//   blocks [2048,2560): BC role — fwd FFT along y (4 kx-lines), spectral
//     multiplies (Hermitian-projection Nyquist masks), BOTH packed inverse
//     FFTs in one round (8 units), coalesced writes Ct[f][b][y][kx] x 1/256.
// NO min-occupancy bound (round 7 lesson: forced VGPR=40 -> 300MB spills).
// ---------------------------------------------------------------------------
#define COL_POOL 51344

__global__ void __launch_bounds__(512)
col_kernel(const float2* __restrict__ At, float2* __restrict__ Ct0,
           float2* __restrict__ Ct1, const float* __restrict__ zsrc,
           const float* __restrict__ Q0, const float* __restrict__ W1,
           const float* __restrict__ b1, const float* __restrict__ W2,
           const float* __restrict__ b2, float* __restrict__ Qb)
{
    __shared__ __align__(16) char pool[COL_POOL];
    const int tid = threadIdx.x;

    if (blockIdx.x < 2048) {
        // ---------------- conv role ----------------
        float*  zt  = (float*)pool;                       // 20 x 28 floats
        float*  ht  = (float*)(pool + 2240);              // 324 cells x 36 f
        float4* w1s = (float4*)(pool + 48896);            // 72 f4
        float4* w2s = (float4*)(pool + 50048);            // 72 f4
        float*  b1s = (float*)(pool + 51200);             // 32 f
        float*  b2s = (float*)(pool + 51328);             // 1 f
        const int cb  = blockIdx.x;
        const int b   = cb & 7;                           // XCD affinity
        const int tile = cb >> 3;                         // 0..255
        const int ty0 = (tile >> 4) * 16, tx0 = (tile & 15) * 16;

        // conv2 mapping + Q0 prefetch (hidden under staging + conv1)
        const int c2chunk = tid >> 3, c2cg = tid & 7;
        const int c2oy = c2chunk >> 2, c2ox4 = (c2chunk & 3) * 4;
        float4 Qpre = make_float4(0.f, 0.f, 0.f, 0.f);
        if (c2cg == 0)
            Qpre = *((const float4*)&Q0[(ty0 + c2oy) * NG + tx0 + c2ox4]);

        if (tid < 72) {
            w1s[tid] = ((const float4*)W1)[tid];
            w2s[tid] = ((const float4*)W2)[tid];
        }
        if (tid < 32) b1s[tid] = b1[tid];
        if (tid == 0) b2s[0] = b2[0];

        // stage z tile: rows ty0-2..ty0+17, f4 cols tx0-4 .. tx0+19 (6 f4/row)
        for (int i = tid; i < 120; i += 512) {
            const int r = i / 6, c4 = i - r * 6;
            const int gy = ty0 - 2 + r;
            const int gx = tx0 - 4 + 4 * c4;      // f4 fully in- or out-of-image
            float4 v = make_float4(0.f, 0.f, 0.f, 0.f);
            if ((unsigned)gy < 256u && (unsigned)gx < 256u)
                v = *((const float4*)&zsrc[(b * NG + gy) * NG + gx]);
            *((float4*)&zt[r * 28 + 4 * c4]) = v;
        }
        __syncthreads();

        // ---- conv1 + ReLU: thread = (chunk of 4 h-cols, cg-pair); 360 active
        if (tid < 360) {
            const int chunk = tid >> 2, cgp = tid & 3;
            const int hy = chunk / 5, hx0 = (chunk - hy * 5) * 4;
            const int k4 = hx0;                    // zt float col of f4 A
            float4 hacc[8];
#pragma unroll
            for (int c = 0; c < 8; ++c) {
                const float bv = b1s[cgp * 8 + c];
                hacc[c] = make_float4(bv, bv, bv, bv);
            }
#pragma unroll
            for (int dy = 0; dy < 3; ++dy) {
                const float* zrow = &zt[(hy + dy) * 28 + k4];
                const float4 Az = *((const float4*)zrow);
                const float4 Bz = *((const float4*)(zrow + 4));
                const float4 W0 = make_float4(Az.z, Az.w, Bz.x, Bz.y);
                const float4 W1v = make_float4(Az.w, Bz.x, Bz.y, Bz.z);
#pragma unroll
                for (int g = 0; g < 2; ++g) {
                    const float4 wa = w1s[(dy * 3 + 0) * 8 + 2 * cgp + g];
                    const float4 wb = w1s[(dy * 3 + 1) * 8 + 2 * cgp + g];
                    const float4 wc = w1s[(dy * 3 + 2) * 8 + 2 * cgp + g];
                    hacc[4*g+0] = f4fma(f4fma(f4fma(hacc[4*g+0], W0, wa.x), W1v, wb.x), Bz, wc.x);
                    hacc[4*g+1] = f4fma(f4fma(f4fma(hacc[4*g+1], W0, wa.y), W1v, wb.y), Bz, wc.y);
                    hacc[4*g+2] = f4fma(f4fma(f4fma(hacc[4*g+2], W0, wa.z), W1v, wb.z), Bz, wc.z);
                    hacc[4*g+3] = f4fma(f4fma(f4fma(hacc[4*g+3], W0, wa.w), W1v, wb.w), Bz, wc.w);
                }
            }
            const int gyh = ty0 - 1 + hy;
            const bool vy = (unsigned)gyh < 256u;
#pragma unroll
            for (int p = 0; p < 4; ++p) {
                const int hxc = hx0 + p;
                if (hxc < 18) {
                    const float mk = (vy && (unsigned)(tx0 - 1 + hxc) < 256u) ? 1.f : 0.f;
                    float* cellp = &ht[(hy * 18 + hxc) * 36];
                    const int s0 = ((2 * cgp + 0 + hxc + hy) & 7) << 2;
                    const int s1 = ((2 * cgp + 1 + hxc + hy) & 7) << 2;
                    const float4 lo = make_float4(
                        mk * fmaxf(comp(hacc[0], p), 0.f), mk * fmaxf(comp(hacc[1], p), 0.f),
                        mk * fmaxf(comp(hacc[2], p), 0.f), mk * fmaxf(comp(hacc[3], p), 0.f));
                    const float4 hi = make_float4(
                        mk * fmaxf(comp(hacc[4], p), 0.f), mk * fmaxf(comp(hacc[5], p), 0.f),
                        mk * fmaxf(comp(hacc[6], p), 0.f), mk * fmaxf(comp(hacc[7], p), 0.f));
                    *((float4*)(cellp + s0)) = lo;
                    *((float4*)(cellp + s1)) = hi;
                }
            }
        }
        __syncthreads();

        // ---- conv2: thread = (chunk of 4 output px, cg); shfl reduce over cg
        {
            const int cg = c2cg;
            const int oy = c2oy, ox4 = c2ox4;
            float q0 = 0.f, q1 = 0.f, q2 = 0.f, q3 = 0.f;
#pragma unroll
            for (int dy = 0; dy < 3; ++dy) {
                const float* hrow = &ht[((oy + dy) * 18 + ox4) * 36];
                const float4 wA = w2s[(dy * 3 + 0) * 8 + cg];
                const float4 wB = w2s[(dy * 3 + 1) * 8 + cg];
                const float4 wC = w2s[(dy * 3 + 2) * 8 + cg];
#pragma unroll
                for (int jj = 0; jj < 6; ++jj) {
                    const float4 hv = *((const float4*)(hrow + jj * 36
                                        + (((cg + ox4 + jj + oy + dy) & 7) << 2)));
                    if (jj <= 3) {
                        const float d = dot4(hv, wA);
                        if (jj == 0) q0 += d; else if (jj == 1) q1 += d;
                        else if (jj == 2) q2 += d; else q3 += d;
                    }
                    if (jj >= 1 && jj <= 4) {
                        const float d = dot4(hv, wB);
                        if (jj == 1) q0 += d; else if (jj == 2) q1 += d;
                        else if (jj == 3) q2 += d; else q3 += d;
                    }
                    if (jj >= 2) {
                        const float d = dot4(hv, wC);
                        if (jj == 2) q0 += d; else if (jj == 3) q1 += d;
                        else if (jj == 4) q2 += d; else q3 += d;
                    }
                }
            }
#pragma unroll
            for (int s = 1; s < 8; s <<= 1) {
                q0 += __shfl_xor(q0, s); q1 += __shfl_xor(q1, s);
                q2 += __shfl_xor(q2, s); q3 += __shfl_xor(q3, s);
            }
            if (cg == 0) {
                const int gy = ty0 + oy, gx = tx0 + ox4;
                const float bb = b2s[0];
                const float4 o = make_float4(
                    Qpre.x + 0.01f * (q0 + bb), Qpre.y + 0.01f * (q1 + bb),
                    Qpre.z + 0.01f * (q2 + bb), Qpre.w + 0.01f * (q3 + bb));
                *((float4*)&Qb[(b * NG + gy) * NG + gx]) = o;
            }
        }
    } else {
        // ---------------- BC role (8 FFT units) ----------------
        float2* tw   = (float2*)pool;                 // 2048
        float2* bufs = (float2*)(pool + 2048);        // 16 x 272 float2
        const int bid = blockIdx.x - 2048;            // 0..511
        const int b  = bid & 7;                       // XCD affinity
        const int kg = bid >> 3;                      // 0..63
        const int j8 = tid >> 6, u = tid & 63;

        init_tw(tw, tid);
        if (j8 < 4) {
            const int kxl = 4 * kg + j8;
            float2* A = bufs + j8 * 272;
            const float2* src = At + ((size_t)(b * NG + kxl)) * NG;
#pragma unroll
            for (int r = 0; r < 4; ++r) {
                const int x = u + 64 * r;
                A[PIDX(x)] = src[x];
            }
        }
        __syncthreads();
        fft256_r4<false>(bufs + j8 * 272, bufs + (4 + (j8 & 3)) * 272, tw, u, j8 < 4);

        if (tid < 256) {
            const int jl = tid >> 6;                  // line 0..3
            const int kxl = 4 * kg + jl;
            float2* A = bufs + jl * 272;
            float2* C = bufs + (8 + jl) * 272;
            const float kxv = (kxl < 128) ? (float)kxl : (float)(kxl - 256);
            const float kxm = (kxl == 128) ? 0.f : kxv;
#pragma unroll
            for (int r = 0; r < 4; ++r) {
                const int ky = u + 64 * r;
                const float kyv = (ky < 128) ? (float)ky : (float)(ky - 256);
                const float kym = (ky == 128) ? 0.f : kyv;
                const float K2 = kxv * kxv + kyv * kyv;
                const float il = (K2 > 0.f) ? (-1.f / K2) : 0.f;
                const float2 Z = A[PIDX(ky)];
                const float ar = -kxm * il, ai = -kym * il;
                A[PIDX(ky)] = make_float2(ar * Z.x - ai * Z.y, ar * Z.y + ai * Z.x);
                C[PIDX(ky)] = make_float2(-kym * Z.x - kxm * Z.y, -kym * Z.y + kxm * Z.x);
            }
        }
        __syncthreads();

        float2* ia = (j8 < 4) ? bufs + j8 * 272 : bufs + (8 + (j8 - 4)) * 272;
        float2* ib = (j8 < 4) ? bufs + (4 + j8) * 272 : bufs + (12 + (j8 - 4)) * 272;
        fft256_r4<true>(ia, ib, tw, u, true);

        const float sc = 1.f / 256.f;
        const int y = tid & 255;
        float2 ov[4];
        if (tid < 256) {
#pragma unroll
            for (int jj = 0; jj < 4; ++jj) {
                const float2 r0 = (bufs + jj * 272)[PIDX(y)];
                ov[jj] = make_float2(r0.x * sc, r0.y * sc);
            }
            float4* dst = (float4*)(Ct0 + ((size_t)(b * NG + y)) * NG + 4 * kg);
            dst[0] = ((float4*)ov)[0];
            dst[1] = ((float4*)ov)[1];
        } else {
#pragma unroll
            for (int jj = 0; jj < 4; ++jj) {
                const float2 r1 = (bufs + (8 + jj) * 272)[PIDX(y)];
                ov[jj] = make_float2(r1.x * sc, r1.y * sc);
            }
            float4* dst = (float4*)(Ct1 + ((size_t)(b * NG + y)) * NG + 4 * kg);
            dst[0] = ((float4*)ov)[0];
            dst[1] = ((float4*)ov)[1];
        }
    }
}

// ---------------------------------------------------------------------------
extern "C" void kernel_launch(void* const* d_in, const int* in_sizes, int n_in,
                              void* d_out, int out_size, void* d_ws, size_t ws_size,
                              hipStream_t stream)
{
    const float* zeta = (const float*)d_in[0];   // (8,256,256)
    const float* Q0   = (const float*)d_in[1];   // (256,256)
    const float* W1   = (const float*)d_in[2];   // (3,3,1,32)
    const float* b1   = (const float*)d_in[3];   // (32,)
    const float* W2   = (const float*)d_in[4];   // (3,3,32,1)
    const float* b2   = (const float*)d_in[5];   // (1,)
    float* outp = (float*)d_out;                 // (8,4,256,256)

    char* ws = (char*)d_ws;
    float*  zws = (float*)(ws);                        // 2 MB (z, in-place)
    float*  Qb  = (float*)(ws + (2u << 20));           // 2 MB
    float2* At  = (float2*)(ws + (4u << 20));          // 4 MB
    float2* Ct0 = (float2*)(ws + (8u << 20));          // 4 MB
    float2* Ct1 = (float2*)(ws + (12u << 20));         // 4 MB
    if (ws_size < (16u << 20)) return;                 // need 16 MB scratch

    // R0: row-FFT of z0 only
    r_kernel<<<1024, 256, 0, stream>>>(zeta, zws, Ct0, Ct1, At, Qb,
                                       nullptr, 0, 1);
    for (int j = 1; j <= 16; ++j) {
        const float* zp = (j == 1) ? zeta : zws;       // z_{j-1}
        col_kernel<<<2560, 512, 0, stream>>>(At, Ct0, Ct1, zp,
                                             Q0, W1, b1, W2, b2, Qb);
        float* op = (j % 4 == 0) ? (outp + (size_t)(j / 4 - 1) * NG * NG)
                                 : nullptr;
        r_kernel<<<1024, 256, 0, stream>>>(zp, zws, Ct0, Ct1, At, Qb,
                                           op, 1, (j < 16) ? 1 : 0);
    }
}